// Round 6
// baseline (925.488 us; speedup 1.0000x reference)
//
#include <hip/hip_runtime.h>
#include <hip/hip_bf16.h>
#include <math.h>

using bf16 = __hip_bfloat16;
typedef __bf16 bf16x8 __attribute__((ext_vector_type(8)));
typedef float  f32x4  __attribute__((ext_vector_type(4)));

#define BK 64   // K-tile; row stride 128B, XOR-swizzled chunks

// ---------------------------------------------------------------------------
// Catmull-Rom spline reconstruction: cp[n_ctrl] -> w[n] (bf16), 8 outputs/thread.
// ---------------------------------------------------------------------------
__global__ void spline_recon8_kernel(const float* __restrict__ cp,
                                     bf16* __restrict__ w,
                                     int n8, int n_ctrl, double step) {
    int k8 = blockIdx.x * blockDim.x + threadIdx.x;
    if (k8 >= n8) return;
    long long kbase = (long long)k8 * 8;
    bf16x8 o;
#pragma unroll
    for (int u = 0; u < 8; ++u) {
        double t = (double)(kbase + u) * step;
        int i = (int)t;
        if (i > n_ctrl - 2) i = n_ctrl - 2;
        float f = (float)(t - (double)i);
        float p0 = cp[i > 0 ? i - 1 : 0];
        float p1 = cp[i];
        float p2 = cp[i + 1];
        float p3 = cp[(i + 2) <= (n_ctrl - 1) ? (i + 2) : (n_ctrl - 1)];
        float f2 = f * f;
        float f3 = f2 * f;
        float v = 0.5f * (2.0f * p1
                          + (p2 - p0) * f
                          + (2.0f * p0 - 5.0f * p1 + 4.0f * p2 - p3) * f2
                          + (3.0f * p1 - p0 - 3.0f * p2 + p3) * f3);
        o[u] = (__bf16)v;
    }
    *reinterpret_cast<bf16x8*>(w + kbase) = o;
}

// fp32 -> bf16 cast, 8 elements/thread
__global__ void cvt_f32_bf16_8_kernel(const float4* __restrict__ x,
                                      bf16* __restrict__ y, int n8) {
    int k = blockIdx.x * blockDim.x + threadIdx.x;
    if (k >= n8) return;
    float4 a = x[2 * k];
    float4 b = x[2 * k + 1];
    bf16x8 o;
    o[0] = (__bf16)a.x; o[1] = (__bf16)a.y; o[2] = (__bf16)a.z; o[3] = (__bf16)a.w;
    o[4] = (__bf16)b.x; o[5] = (__bf16)b.y; o[6] = (__bf16)b.z; o[7] = (__bf16)b.w;
    *reinterpret_cast<bf16x8*>(y + (long long)k * 8) = o;
}

__device__ __forceinline__ void async_load16(const bf16* g, bf16* l) {
    __builtin_amdgcn_global_load_lds(
        (const __attribute__((address_space(1))) void*)g,
        (__attribute__((address_space(3))) void*)l,
        16, 0, 0);
}

// ---------------------------------------------------------------------------
// Fused gate+up GEMM, R6: 256 threads = 4 waves, block tile 128x128,
// WAVE tile 64x128 (acc 4x8 f32x4 = 128 AGPR) -> FLOP/LDS-byte 42.7 vs 32.
// Waves 0-1: gate (rows 0-63 / 64-127); waves 2-3: up.
// BK=64, XOR chunk swizzle LDS[row][cc] = G[row][cc^(row&7)].
// ---------------------------------------------------------------------------
__global__ __launch_bounds__(256, 2) void fused_gate_up_kernel(
    const bf16* __restrict__ A,    // X  [M, K]
    const bf16* __restrict__ Bg,   // Wg [N, K]
    const bf16* __restrict__ Bu,   // Wu [N, K]
    bf16* __restrict__ C,          // inter [M, N]
    int M, int N, int K) {
    __shared__ __align__(16) bf16 smem[3 * 128 * BK];   // 48 KB
    bf16* As  = smem;                                   // [128][64]
    bf16* Bgs = smem + 8192;
    bf16* Bus = smem + 16384;

    const int tid  = threadIdx.x;
    const int lane = tid & 63;
    const int wave = tid >> 6;          // 0..3
    const int wm   = (wave & 1) * 64;
    const bool is_gate = wave < 2;

    const long long brow = (long long)blockIdx.y * 128;
    const long long bcol = (long long)blockIdx.x * 128;

    // staging: each tile = 1024 chunks of 16B; 4 issues/thread/tile.
    // issue r covers rows r*32 + (tid>>3); colchunk = tid&7 (LDS),
    // global colchunk = (tid&7) ^ (row&7); (row&7) invariant over r (+32).
    const int srow = tid >> 3;                       // 0..31
    const int skb  = ((tid & 7) ^ (srow & 7)) * 8;
    const bf16* ga = A  + (brow + srow) * (long long)K + skb;
    const bf16* gg = Bg + (bcol + srow) * (long long)K + skb;
    const bf16* gu = Bu + (bcol + srow) * (long long)K + skb;
    const long long rstep = 32LL * K;

    const bf16* Bsel = is_gate ? Bgs : Bus;
    const int fm = wm + (lane & 15);     // A row for frags (i*16 added)
    const int fnb = lane & 15;           // B row base (j*16 added)
    const int qk = lane >> 4;            // k-quad 0..3
    const int ccAbase = fm & 7;          // invariant over i (+16)
    const int ccBbase = fnb & 7;         // invariant over j (+16)

    f32x4 acc[4][8] = {};

    for (int k0 = 0; k0 < K; k0 += BK) {
#pragma unroll
        for (int r = 0; r < 4; ++r) {
            async_load16(ga + r * rstep, As  + r * 2048 + tid * 8);
            async_load16(gg + r * rstep, Bgs + r * 2048 + tid * 8);
            async_load16(gu + r * rstep, Bus + r * 2048 + tid * 8);
        }
        ga += BK; gg += BK; gu += BK;
        __syncthreads();   // drains vmcnt for global_load_lds

#pragma unroll
        for (int h = 0; h < 2; ++h) {
            const int hc = (h << 2) | qk;          // wanted colchunk 0..7
            const int ccA = (hc ^ ccAbase) * 8;
            const int ccB = (hc ^ ccBbase) * 8;
            bf16x8 afr[4], bfr[8];
#pragma unroll
            for (int i = 0; i < 4; ++i)
                afr[i] = *reinterpret_cast<const bf16x8*>(
                    &As[(fm + i * 16) * BK + ccA]);
#pragma unroll
            for (int j = 0; j < 8; ++j)
                bfr[j] = *reinterpret_cast<const bf16x8*>(
                    &Bsel[(fnb + j * 16) * BK + ccB]);
#pragma unroll
            for (int i = 0; i < 4; ++i)
#pragma unroll
                for (int j = 0; j < 8; ++j)
                    acc[i][j] = __builtin_amdgcn_mfma_f32_16x16x32_bf16(
                        afr[i], bfr[j], acc[i][j], 0, 0, 0);
        }
        __syncthreads();
    }

    // Epilogue: silu(gate)*up through LDS Epi[128][128] (reuses smem, 32 KB)
    bf16* Epi = smem;
    if (is_gate) {
#pragma unroll
        for (int i = 0; i < 4; ++i)
#pragma unroll
            for (int j = 0; j < 8; ++j)
#pragma unroll
                for (int r = 0; r < 4; ++r) {
                    int row = wm + i * 16 + qk * 4 + r;
                    int col = j * 16 + (lane & 15);
                    float v = acc[i][j][r];
                    float s = v / (1.0f + expf(-v));
                    Epi[row * 128 + col] = __float2bfloat16(s);
                }
    }
    __syncthreads();
    if (!is_gate) {
#pragma unroll
        for (int i = 0; i < 4; ++i)
#pragma unroll
            for (int j = 0; j < 8; ++j)
#pragma unroll
                for (int r = 0; r < 4; ++r) {
                    int row = wm + i * 16 + qk * 4 + r;
                    int col = j * 16 + (lane & 15);
                    float s = __bfloat162float(Epi[row * 128 + col]);
                    float v = s * acc[i][j][r];
                    C[(brow + row) * (long long)N + bcol + col] = __float2bfloat16(v);
                }
    }
}

// ---------------------------------------------------------------------------
// down GEMM, R6: 256 threads = 4 waves, block tile 128(M) x 256(N),
// wave tile 64x128. fp32 output.
// ---------------------------------------------------------------------------
__global__ __launch_bounds__(256, 2) void gemm_down2_kernel(
    const bf16* __restrict__ A,   // inter [M, K]
    const bf16* __restrict__ B,   // Wd    [N, K]
    float* __restrict__ C,        // out   [M, N]
    int M, int N, int K) {
    __shared__ __align__(16) bf16 As[128 * BK];   // 16 KB
    __shared__ __align__(16) bf16 Bs[256 * BK];   // 32 KB

    const int tid  = threadIdx.x;
    const int lane = tid & 63;
    const int wave = tid >> 6;           // 0..3
    const int wm   = (wave >> 1) * 64;
    const int wn   = (wave & 1) * 128;

    const long long brow = (long long)blockIdx.y * 128;
    const long long bcol = (long long)blockIdx.x * 256;

    const int srow = tid >> 3;                        // 0..31
    const int skb  = ((tid & 7) ^ (srow & 7)) * 8;
    const bf16* ga = A + (brow + srow) * (long long)K + skb;
    const bf16* gb = B + (bcol + srow) * (long long)K + skb;
    const long long rstep = 32LL * K;

    const int fm = wm + (lane & 15);
    const int fnb = wn + (lane & 15);
    const int qk = lane >> 4;
    const int ccAbase = fm & 7;
    const int ccBbase = fnb & 7;

    f32x4 acc[4][8] = {};

    for (int k0 = 0; k0 < K; k0 += BK) {
#pragma unroll
        for (int r = 0; r < 4; ++r)
            async_load16(ga + r * rstep, As + r * 2048 + tid * 8);
#pragma unroll
        for (int r = 0; r < 8; ++r)
            async_load16(gb + r * rstep, Bs + r * 2048 + tid * 8);
        ga += BK; gb += BK;
        __syncthreads();

#pragma unroll
        for (int h = 0; h < 2; ++h) {
            const int hc = (h << 2) | qk;
            const int ccA = (hc ^ ccAbase) * 8;
            const int ccB = (hc ^ ccBbase) * 8;
            bf16x8 afr[4], bfr[8];
#pragma unroll
            for (int i = 0; i < 4; ++i)
                afr[i] = *reinterpret_cast<const bf16x8*>(
                    &As[(fm + i * 16) * BK + ccA]);
#pragma unroll
            for (int j = 0; j < 8; ++j)
                bfr[j] = *reinterpret_cast<const bf16x8*>(
                    &Bs[(fnb + j * 16) * BK + ccB]);
#pragma unroll
            for (int i = 0; i < 4; ++i)
#pragma unroll
                for (int j = 0; j < 8; ++j)
                    acc[i][j] = __builtin_amdgcn_mfma_f32_16x16x32_bf16(
                        afr[i], bfr[j], acc[i][j], 0, 0, 0);
        }
        __syncthreads();
    }

#pragma unroll
    for (int i = 0; i < 4; ++i)
#pragma unroll
        for (int j = 0; j < 8; ++j)
#pragma unroll
            for (int r = 0; r < 4; ++r) {
                long long row = brow + wm + i * 16 + qk * 4 + r;
                long long col = bcol + wn + j * 16 + (lane & 15);
                C[row * N + col] = acc[i][j][r];
            }
}

// ---------------------------------------------------------------------------
extern "C" void kernel_launch(void* const* d_in, const int* in_sizes, int n_in,
                              void* d_out, int out_size, void* d_ws, size_t ws_size,
                              hipStream_t stream) {
    const float* hs  = (const float*)d_in[0];   // [4,2048,2048] fp32
    const float* gcp = (const float*)d_in[1];
    const float* ucp = (const float*)d_in[2];
    const float* dcp = (const float*)d_in[3];

    const int M = 8192;        // 4*2048 tokens
    const int H = 2048;
    const int I = 8192;
    const int NW = H * I;
    const int n_ctrl_g = in_sizes[1];
    const int n_ctrl_u = in_sizes[2];
    const int n_ctrl_d = in_sizes[3];

    // workspace layout (all bf16): Xb | Wg | Wu | Wd | inter
    bf16* Xb    = (bf16*)d_ws;
    bf16* Wg    = Xb + (size_t)M * H;
    bf16* Wu    = Wg + (size_t)NW;
    bf16* Wd    = Wu + (size_t)NW;
    bf16* inter = Wd + (size_t)NW;

    const int nX8 = (M * H) / 8;
    cvt_f32_bf16_8_kernel<<<(nX8 + 255) / 256, 256, 0, stream>>>(
        (const float4*)hs, Xb, nX8);

    double step_g = (double)(n_ctrl_g - 1) / (double)(NW - 1);
    double step_u = (double)(n_ctrl_u - 1) / (double)(NW - 1);
    double step_d = (double)(n_ctrl_d - 1) / (double)(NW - 1);
    const int n8 = NW / 8;
    spline_recon8_kernel<<<(n8 + 255) / 256, 256, 0, stream>>>(gcp, Wg, n8, n_ctrl_g, step_g);
    spline_recon8_kernel<<<(n8 + 255) / 256, 256, 0, stream>>>(ucp, Wu, n8, n_ctrl_u, step_u);
    spline_recon8_kernel<<<(n8 + 255) / 256, 256, 0, stream>>>(dcp, Wd, n8, n_ctrl_d, step_d);

    // fused gate+up: inter = silu(X.Wg^T) * (X.Wu^T)   [M, I]
    fused_gate_up_kernel<<<dim3(I / 128, M / 128), 256, 0, stream>>>(
        Xb, Wg, Wu, inter, M, I, H);

    // down: out = inter . Wd^T  (fp32)   [M, H]
    gemm_down2_kernel<<<dim3(H / 256, M / 128), 256, 0, stream>>>(
        inter, Wd, (float*)d_out, M, H, I);
}

// Round 7
// 915.114 us; speedup vs baseline: 1.0113x; 1.0113x over previous
//
#include <hip/hip_runtime.h>
#include <hip/hip_bf16.h>
#include <math.h>

using bf16 = __hip_bfloat16;
typedef __bf16 bf16x8 __attribute__((ext_vector_type(8)));
typedef float  f32x4  __attribute__((ext_vector_type(4)));

#define BK 64   // K-tile; row stride 128B, XOR-swizzled chunks

// ---------------------------------------------------------------------------
// Catmull-Rom spline reconstruction: cp[n_ctrl] -> w[n] (bf16), 8 outputs/thread.
// ---------------------------------------------------------------------------
__global__ void spline_recon8_kernel(const float* __restrict__ cp,
                                     bf16* __restrict__ w,
                                     int n8, int n_ctrl, double step) {
    int k8 = blockIdx.x * blockDim.x + threadIdx.x;
    if (k8 >= n8) return;
    long long kbase = (long long)k8 * 8;
    bf16x8 o;
#pragma unroll
    for (int u = 0; u < 8; ++u) {
        double t = (double)(kbase + u) * step;
        int i = (int)t;
        if (i > n_ctrl - 2) i = n_ctrl - 2;
        float f = (float)(t - (double)i);
        float p0 = cp[i > 0 ? i - 1 : 0];
        float p1 = cp[i];
        float p2 = cp[i + 1];
        float p3 = cp[(i + 2) <= (n_ctrl - 1) ? (i + 2) : (n_ctrl - 1)];
        float f2 = f * f;
        float f3 = f2 * f;
        float v = 0.5f * (2.0f * p1
                          + (p2 - p0) * f
                          + (2.0f * p0 - 5.0f * p1 + 4.0f * p2 - p3) * f2
                          + (3.0f * p1 - p0 - 3.0f * p2 + p3) * f3);
        o[u] = (__bf16)v;
    }
    *reinterpret_cast<bf16x8*>(w + kbase) = o;
}

// fp32 -> bf16 cast, 8 elements/thread
__global__ void cvt_f32_bf16_8_kernel(const float4* __restrict__ x,
                                      bf16* __restrict__ y, int n8) {
    int k = blockIdx.x * blockDim.x + threadIdx.x;
    if (k >= n8) return;
    float4 a = x[2 * k];
    float4 b = x[2 * k + 1];
    bf16x8 o;
    o[0] = (__bf16)a.x; o[1] = (__bf16)a.y; o[2] = (__bf16)a.z; o[3] = (__bf16)a.w;
    o[4] = (__bf16)b.x; o[5] = (__bf16)b.y; o[6] = (__bf16)b.z; o[7] = (__bf16)b.w;
    *reinterpret_cast<bf16x8*>(y + (long long)k * 8) = o;
}

__device__ __forceinline__ void async_load16(const bf16* g, bf16* l) {
    __builtin_amdgcn_global_load_lds(
        (const __attribute__((address_space(1))) void*)g,
        (__attribute__((address_space(3))) void*)l,
        16, 0, 0);
}

// ---------------------------------------------------------------------------
// Fused gate+up GEMM (R5 version, measured 492 us / 1117 TF):
// 512 threads = 8 waves: waves 0-3 gate, 4-7 up; shared As stage.
// BK=64, tiles [128][64] bf16, XOR-swizzled: LDS[row][cc] = G[row][cc^(row&7)]
// (swizzle applied on the GLOBAL source address; LDS dest stays lane-linear).
// NOTE (R6): 64x128 wave tile regressed (236 regs/wave -> 8 waves/CU); keep 64x64.
// ---------------------------------------------------------------------------
__global__ __launch_bounds__(512, 4) void fused_gate_up_kernel(
    const bf16* __restrict__ A,    // X  [M, K]
    const bf16* __restrict__ Bg,   // Wg [N, K]
    const bf16* __restrict__ Bu,   // Wu [N, K]
    bf16* __restrict__ C,          // inter [M, N]
    int M, int N, int K) {
    __shared__ __align__(16) bf16 smem[3 * 128 * BK];   // 48 KB
    bf16* As  = smem;
    bf16* Bgs = smem + 128 * BK;
    bf16* Bus = smem + 2 * 128 * BK;

    const int tid  = threadIdx.x;
    const int lane = tid & 63;
    const int wave = tid >> 6;
    const int wq   = wave & 3;
    const int wm   = (wq >> 1) * 64;
    const int wn   = (wq & 1) * 64;
    const bool is_gate = wave < 4;

    const long long brow = (long long)blockIdx.y * 128;
    const long long bcol = (long long)blockIdx.x * 128;

    const int srow = tid >> 3;                       // 0..63
    const int skb  = ((tid & 7) ^ (srow & 7)) * 8;   // swizzled global col (elems)
    const bf16* ga0 = A  + (brow + srow) * (long long)K + skb;
    const bf16* ga1 = A  + (brow + srow + 64) * (long long)K + skb;
    const bf16* gg0 = Bg + (bcol + srow) * (long long)K + skb;
    const bf16* gg1 = Bg + (bcol + srow + 64) * (long long)K + skb;
    const bf16* gu0 = Bu + (bcol + srow) * (long long)K + skb;
    const bf16* gu1 = Bu + (bcol + srow + 64) * (long long)K + skb;
    bf16* la0 = As  + tid * 8;
    bf16* la1 = As  + 4096 + tid * 8;
    bf16* lg0 = Bgs + tid * 8;
    bf16* lg1 = Bgs + 4096 + tid * 8;
    bf16* lu0 = Bus + tid * 8;
    bf16* lu1 = Bus + 4096 + tid * 8;

    const bf16* Bsel = is_gate ? Bgs : Bus;
    const int fm = wm + (lane & 15);
    const int fn = wn + (lane & 15);
    const int qk = lane >> 4;              // 0..3 (k-quad)

    f32x4 acc[4][4] = {};

    for (int k0 = 0; k0 < K; k0 += BK) {
        async_load16(ga0, la0); ga0 += BK;
        async_load16(ga1, la1); ga1 += BK;
        async_load16(gg0, lg0); gg0 += BK;
        async_load16(gg1, lg1); gg1 += BK;
        async_load16(gu0, lu0); gu0 += BK;
        async_load16(gu1, lu1); gu1 += BK;
        __syncthreads();   // drains vmcnt for global_load_lds

#pragma unroll
        for (int h = 0; h < 2; ++h) {
            bf16x8 afr[4], bfr[4];
            const int hc = (h << 2) | qk;          // wanted colchunk 0..7
            const int ccA = (hc ^ (fm & 7)) * 8;   // fm&7 invariant over i (+16)
            const int ccB = (hc ^ (fn & 7)) * 8;
#pragma unroll
            for (int i = 0; i < 4; ++i)
                afr[i] = *reinterpret_cast<const bf16x8*>(
                    &As[(fm + i * 16) * BK + ccA]);
#pragma unroll
            for (int j = 0; j < 4; ++j)
                bfr[j] = *reinterpret_cast<const bf16x8*>(
                    &Bsel[(fn + j * 16) * BK + ccB]);
#pragma unroll
            for (int i = 0; i < 4; ++i)
#pragma unroll
                for (int j = 0; j < 4; ++j)
                    acc[i][j] = __builtin_amdgcn_mfma_f32_16x16x32_bf16(
                        afr[i], bfr[j], acc[i][j], 0, 0, 0);
        }
        __syncthreads();
    }

    // Epilogue: combine silu(gate)*up through LDS (reuses smem as Epi[128][128])
    bf16* Epi = smem;
    if (is_gate) {
#pragma unroll
        for (int i = 0; i < 4; ++i)
#pragma unroll
            for (int j = 0; j < 4; ++j)
#pragma unroll
                for (int r = 0; r < 4; ++r) {
                    int row = wm + i * 16 + (lane >> 4) * 4 + r;
                    int col = wn + j * 16 + (lane & 15);
                    float v = acc[i][j][r];
                    float s = v / (1.0f + expf(-v));
                    Epi[row * 128 + col] = __float2bfloat16(s);
                }
    }
    __syncthreads();
    if (!is_gate) {
#pragma unroll
        for (int i = 0; i < 4; ++i)
#pragma unroll
            for (int j = 0; j < 4; ++j)
#pragma unroll
                for (int r = 0; r < 4; ++r) {
                    int row = wm + i * 16 + (lane >> 4) * 4 + r;
                    int col = wn + j * 16 + (lane & 15);
                    float s = __bfloat162float(Epi[row * 128 + col]);
                    float v = s * acc[i][j][r];
                    C[(brow + row) * (long long)N + bcol + col] = __float2bfloat16(v);
                }
    }
}

// ---------------------------------------------------------------------------
// down GEMM, R7: 256 threads = 4 waves (2x2 of 64x64), block tile 128x128,
// BK=64 + XOR swizzle. Grid 16x64 = 1024 blocks; ~124 regs/wave ->
// 4 waves/SIMD -> 4 resident blocks/CU (LDS 32KB*4=128KB) with 2x dispatch
// oversubscription — the conditions under which the fused kernel hit 1117 TF.
// ---------------------------------------------------------------------------
__global__ __launch_bounds__(256, 4) void gemm_down3_kernel(
    const bf16* __restrict__ A,   // inter [M, K]
    const bf16* __restrict__ B,   // Wd    [N, K]
    float* __restrict__ C,        // out   [M, N]
    int M, int N, int K) {
    __shared__ __align__(16) bf16 As[128 * BK];   // 16 KB
    __shared__ __align__(16) bf16 Bs[128 * BK];   // 16 KB

    const int tid  = threadIdx.x;
    const int lane = tid & 63;
    const int wave = tid >> 6;           // 0..3
    const int wm   = (wave >> 1) * 64;
    const int wn   = (wave & 1) * 64;

    const long long brow = (long long)blockIdx.y * 128;
    const long long bcol = (long long)blockIdx.x * 128;

    // staging: per tile 1024 chunks of 16B; 4 issues/thread/tile.
    // issue r covers rows srow + r*32; (row&7) invariant over r.
    const int srow = tid >> 3;                        // 0..31
    const int skb  = ((tid & 7) ^ (srow & 7)) * 8;
    const bf16* ga = A + (brow + srow) * (long long)K + skb;
    const bf16* gb = B + (bcol + srow) * (long long)K + skb;
    const long long rstep = 32LL * K;

    const int fm = wm + (lane & 15);
    const int fn = wn + (lane & 15);
    const int qk = lane >> 4;

    f32x4 acc[4][4] = {};

    for (int k0 = 0; k0 < K; k0 += BK) {
#pragma unroll
        for (int r = 0; r < 4; ++r) {
            async_load16(ga + r * rstep, As + r * 2048 + tid * 8);
            async_load16(gb + r * rstep, Bs + r * 2048 + tid * 8);
        }
        ga += BK; gb += BK;
        __syncthreads();

#pragma unroll
        for (int h = 0; h < 2; ++h) {
            bf16x8 afr[4], bfr[4];
            const int hc = (h << 2) | qk;
            const int ccA = (hc ^ (fm & 7)) * 8;
            const int ccB = (hc ^ (fn & 7)) * 8;
#pragma unroll
            for (int i = 0; i < 4; ++i)
                afr[i] = *reinterpret_cast<const bf16x8*>(
                    &As[(fm + i * 16) * BK + ccA]);
#pragma unroll
            for (int j = 0; j < 4; ++j)
                bfr[j] = *reinterpret_cast<const bf16x8*>(
                    &Bs[(fn + j * 16) * BK + ccB]);
#pragma unroll
            for (int i = 0; i < 4; ++i)
#pragma unroll
                for (int j = 0; j < 4; ++j)
                    acc[i][j] = __builtin_amdgcn_mfma_f32_16x16x32_bf16(
                        afr[i], bfr[j], acc[i][j], 0, 0, 0);
        }
        __syncthreads();
    }

#pragma unroll
    for (int i = 0; i < 4; ++i)
#pragma unroll
        for (int j = 0; j < 4; ++j)
#pragma unroll
            for (int r = 0; r < 4; ++r) {
                long long row = brow + wm + i * 16 + qk * 4 + r;
                long long col = bcol + wn + j * 16 + (lane & 15);
                C[row * N + col] = acc[i][j][r];
            }
}

// ---------------------------------------------------------------------------
extern "C" void kernel_launch(void* const* d_in, const int* in_sizes, int n_in,
                              void* d_out, int out_size, void* d_ws, size_t ws_size,
                              hipStream_t stream) {
    const float* hs  = (const float*)d_in[0];   // [4,2048,2048] fp32
    const float* gcp = (const float*)d_in[1];
    const float* ucp = (const float*)d_in[2];
    const float* dcp = (const float*)d_in[3];

    const int M = 8192;        // 4*2048 tokens
    const int H = 2048;
    const int I = 8192;
    const int NW = H * I;
    const int n_ctrl_g = in_sizes[1];
    const int n_ctrl_u = in_sizes[2];
    const int n_ctrl_d = in_sizes[3];

    // workspace layout (all bf16): Xb | Wg | Wu | Wd | inter
    bf16* Xb    = (bf16*)d_ws;
    bf16* Wg    = Xb + (size_t)M * H;
    bf16* Wu    = Wg + (size_t)NW;
    bf16* Wd    = Wu + (size_t)NW;
    bf16* inter = Wd + (size_t)NW;

    const int nX8 = (M * H) / 8;
    cvt_f32_bf16_8_kernel<<<(nX8 + 255) / 256, 256, 0, stream>>>(
        (const float4*)hs, Xb, nX8);

    double step_g = (double)(n_ctrl_g - 1) / (double)(NW - 1);
    double step_u = (double)(n_ctrl_u - 1) / (double)(NW - 1);
    double step_d = (double)(n_ctrl_d - 1) / (double)(NW - 1);
    const int n8 = NW / 8;
    spline_recon8_kernel<<<(n8 + 255) / 256, 256, 0, stream>>>(gcp, Wg, n8, n_ctrl_g, step_g);
    spline_recon8_kernel<<<(n8 + 255) / 256, 256, 0, stream>>>(ucp, Wu, n8, n_ctrl_u, step_u);
    spline_recon8_kernel<<<(n8 + 255) / 256, 256, 0, stream>>>(dcp, Wd, n8, n_ctrl_d, step_d);

    // fused gate+up: inter = silu(X.Wg^T) * (X.Wu^T)   [M, I]
    fused_gate_up_kernel<<<dim3(I / 128, M / 128), 512, 0, stream>>>(
        Xb, Wg, Wu, inter, M, I, H);

    // down: out = inter . Wd^T  (fp32)   [M, H], 128x128 tiles, 1024 blocks
    gemm_down3_kernel<<<dim3(H / 128, M / 128), 256, 0, stream>>>(
        inter, Wd, (float*)d_out, M, H, I);
}